// Round 12
// baseline (188.464 us; speedup 1.0000x reference)
//
#include <hip/hip_runtime.h>

typedef unsigned short ushort_t;
typedef __attribute__((ext_vector_type(8))) short short8;
typedef __attribute__((ext_vector_type(4))) float f32x4;
typedef __attribute__((ext_vector_type(16))) float f32x16;
typedef __attribute__((ext_vector_type(4))) float float4v;
typedef __attribute__((ext_vector_type(4))) unsigned short ushortx4;
typedef __attribute__((ext_vector_type(4))) unsigned int uint4v;

#define AS1 __attribute__((address_space(1)))
#define AS3 __attribute__((address_space(3)))

#define B_ 4
#define N_ 2048
#define C_ 1024
#define H_ 16
#define HD_ 64
#define M_TOT 8192
#define N3_ 3072

// q scale: 1/sqrt(64) * log2(e) so softmax runs in exp2 domain
#define QSCALE 0.18033688011112042f

__device__ __forceinline__ unsigned short f2bf(float f) {
    unsigned int u = __float_as_uint(f);
    u += 0x7fffu + ((u >> 16) & 1u);
    return (unsigned short)(u >> 16);
}

// merged cast: x, w_qkv, w_out -> bf16 in one launch (saves 2 launch gaps)
__global__ __launch_bounds__(256) void cast3_f32_bf16(const float* __restrict__ xa,
                                                      const float* __restrict__ xb,
                                                      const float* __restrict__ xc,
                                                      ushort_t* __restrict__ oa,
                                                      ushort_t* __restrict__ ob,
                                                      ushort_t* __restrict__ oc,
                                                      int n4a, int n4b, int n4c) {
    int i = blockIdx.x * blockDim.x + threadIdx.x;
    const int stride = gridDim.x * blockDim.x;
    const int tot = n4a + n4b + n4c;
    for (; i < tot; i += stride) {
        const float4v* src;
        ushortx4* dst;
        int j = i;
        if (j < n4a) { src = (const float4v*)xa; dst = (ushortx4*)oa; }
        else if ((j -= n4a) < n4b) { src = (const float4v*)xb; dst = (ushortx4*)ob; }
        else { j -= n4b; src = (const float4v*)xc; dst = (ushortx4*)oc; }
        float4v v = src[j];
        ushortx4 o;
        o[0] = f2bf(v[0]); o[1] = f2bf(v[1]); o[2] = f2bf(v[2]); o[3] = f2bf(v[3]);
        dst[j] = o;
    }
}

// Fragment-major layouts for attention (lane = 64-lane wave index, 32x32x16 MFMA):
//  Q/K element (bh, n, hd): blk=n>>5, ks=hd>>4, lane=(n&31)+32*((hd>>3)&1), e=hd&7
//    addr = ((bh*64+blk)*4+ks)*512 + lane*8 + e
//  V element (bh, kv, d): t=kv>>5, dt=d>>5, kb=(kv>>4)&1, lane=(d&31)+32*((kv>>3)&1), e=kv&7
//    addr = (((bh*64+t)*2+dt)*2+kb)*512 + lane*8 + e

// ---------------------------------------------------------------------------
// gemm4w: C = A @ B^T. BM=128, BN=128, BK=64. 256 threads = 4 waves (2M x 2N),
// per-wave 64x64 (acc[4][4]). 2 LDS buffers x 32KB (64KB static) -> 2 blocks/CU:
// cross-block decorrelation covers barrier/vmcnt stalls (the 96KB/1-block
// gemm8p froze the whole CU at each barrier). Same counted-vmcnt 2-phase
// schedule (vmcnt(4), never 0 in steady state), same 2-way-free XOR swizzle
// (slot ^= (row>>1)&3) applied via pre-swizzled global source + linear dest.
// EPI 0: scatter qkv fragment-major (q *QSCALE).  EPI 1: f32 + bias.
// ---------------------------------------------------------------------------
template <int EPI>
__global__ __launch_bounds__(256, 2) void gemm4w(const ushort_t* __restrict__ A,
                                                 const ushort_t* __restrict__ Bw,
                                                 ushort_t* __restrict__ o0,
                                                 ushort_t* __restrict__ o1,
                                                 ushort_t* __restrict__ o2,
                                                 float* __restrict__ outf,
                                                 const float* __restrict__ bias,
                                                 int K, int NBX) {
    __shared__ ushort_t smem[2][16384];  // per buf: A kh0|kh1 (2x4096), B kh0|kh1
    const int tid = threadIdx.x;
    const int lane = tid & 63;
    const int wid = tid >> 6;
    const int l15 = lane & 15, lg = lane >> 4;
    const int wr = wid >> 1, wc = wid & 1;

    // XCD-bijective swizzle (gridDim.x % 8 == 0 for both gemms)
    const int wg = blockIdx.x;
    const int id = (wg & 7) * ((int)gridDim.x >> 3) + (wg >> 3);
    const int by = id / NBX, bx = id - by * NBX;
    const int m0 = by * 128, n0 = bx * 128;

    // read-side swizzle: logical slot lg lives at dest slot lg ^ ((row>>1)&3)
    const int koff = ((lg ^ ((lane >> 1) & 3)) << 3);
    // stage-side: dest slot tid&3 holds logical slot (tid&3) ^ ((row>>1)&3)
    const int slotsrc = (tid & 3) ^ ((tid >> 3) & 3);

    auto stageA = [&](int q, int tt, int kh) {
#pragma unroll
        for (int j = 0; j < 2; ++j) {
            const ushort_t* src = A + (size_t)(m0 + j * 64 + (tid >> 2)) * K + tt * 64 +
                                  kh * 32 + slotsrc * 8;
            ushort_t* dst = &smem[q][kh * 4096 + j * 2048 + tid * 8];
            __builtin_amdgcn_global_load_lds((const AS1 void*)src, (AS3 void*)dst, 16, 0, 0);
        }
    };
    auto stageB = [&](int q, int tt, int kh) {
#pragma unroll
        for (int j = 0; j < 2; ++j) {
            const ushort_t* src = Bw + (size_t)(n0 + j * 64 + (tid >> 2)) * K + tt * 64 +
                                  kh * 32 + slotsrc * 8;
            ushort_t* dst = &smem[q][8192 + kh * 4096 + j * 2048 + tid * 8];
            __builtin_amdgcn_global_load_lds((const AS1 void*)src, (AS3 void*)dst, 16, 0, 0);
        }
    };

    f32x4 acc[4][4] = {};

    auto phase = [&](int p, int kh) {
        const ushort_t* Ab = &smem[p][kh * 4096];
        const ushort_t* Bb = &smem[p][8192 + kh * 4096];
        short8 af[4], bfr[4];
#pragma unroll
        for (int rt = 0; rt < 4; ++rt)
            af[rt] = *(const short8*)(Ab + (wr * 64 + rt * 16 + l15) * 32 + koff);
#pragma unroll
        for (int ni = 0; ni < 4; ++ni)
            bfr[ni] = *(const short8*)(Bb + (wc * 64 + ni * 16 + l15) * 32 + koff);
        __builtin_amdgcn_s_setprio(1);
#pragma unroll
        for (int rt = 0; rt < 4; ++rt)
#pragma unroll
            for (int ni = 0; ni < 4; ++ni)
                acc[rt][ni] = __builtin_amdgcn_mfma_f32_16x16x32_bf16(af[rt], bfr[ni],
                                                                      acc[rt][ni], 0, 0, 0);
        __builtin_amdgcn_s_setprio(0);
    };

    // prologue: full tile 0 into buf 0 (8 calls)
    stageA(0, 0, 0); stageB(0, 0, 0);
    stageA(0, 0, 1); stageB(0, 0, 1);

    const int NT = K >> 6;
    for (int t = 0; t < NT; ++t) {
        const int p = t & 1, q = p ^ 1;
        if (t + 1 < NT) {
            stageA(q, t + 1, 0); stageB(q, t + 1, 0);
            __builtin_amdgcn_sched_barrier(0);
            asm volatile("s_waitcnt vmcnt(4)");
        } else {
            asm volatile("s_waitcnt vmcnt(0)");
        }
        __builtin_amdgcn_sched_barrier(0);
        __builtin_amdgcn_s_barrier();          // tile t fully staged
        __builtin_amdgcn_sched_barrier(0);
        phase(p, 0);
        if (t + 1 < NT) {
            stageA(q, t + 1, 1); stageB(q, t + 1, 1);
        }
        __builtin_amdgcn_sched_barrier(0);
        __builtin_amdgcn_s_barrier();
        __builtin_amdgcn_sched_barrier(0);
        phase(p, 1);
    }

    if (EPI == 0) {
        const int sel = bx >> 3;  // 0=q 1=k 2=v, uniform per block (128-col blocks)
#pragma unroll
        for (int mi = 0; mi < 4; ++mi) {
            const int r0 = m0 + wr * 64 + mi * 16 + lg * 4;
            const int b = r0 >> 11, n = r0 & 2047;
            const int blk = n >> 5, nlo = n & 31;
#pragma unroll
            for (int ni = 0; ni < 4; ++ni) {
                const int cq = (bx & 7) * 128 + wc * 64 + ni * 16 + l15;
                const int h = cq >> 6, hd = cq & 63;
                const int bh = b * H_ + h;
                f32x4 a = acc[mi][ni];
                if (sel == 2) {
                    size_t base = (((size_t)(bh * 64 + blk) * 2 + (hd >> 5)) * 2 +
                                   ((n >> 4) & 1)) * 512 +
                                  ((hd & 31) + ((n >> 3) & 1) * 32) * 8 + (n & 7);
                    ushortx4 pk;
#pragma unroll
                    for (int j = 0; j < 4; ++j) pk[j] = f2bf(a[j]);
                    *(ushortx4*)(&o2[base]) = pk;
                } else {
                    size_t base = ((size_t)(bh * 64 + blk) * 4 + (hd >> 4)) * 512 +
                                  (nlo + ((hd >> 3) & 1) * 32) * 8 + (hd & 7);
                    if (sel == 0) {
#pragma unroll
                        for (int j = 0; j < 4; ++j) o0[base + j * 8] = f2bf(a[j] * QSCALE);
                    } else {
#pragma unroll
                        for (int j = 0; j < 4; ++j) o1[base + j * 8] = f2bf(a[j]);
                    }
                }
            }
        }
    } else {
#pragma unroll
        for (int ni = 0; ni < 4; ++ni) {
            const int c = n0 + wc * 64 + ni * 16 + l15;
            const float bv = bias[c];
#pragma unroll
            for (int mi = 0; mi < 4; ++mi) {
                const int r0 = m0 + wr * 64 + mi * 16 + lg * 4;
                f32x4 a = acc[mi][ni];
#pragma unroll
                for (int j = 0; j < 4; ++j)
                    outf[(size_t)(r0 + j) * C_ + c] = a[j] + bv;
            }
        }
    }
}

// Flash attention (v4 structure + ones-MFMA row-sum): fragment-major coalesced
// loads, 32x32x16 MFMA, fixed-base softmax (P row-sum on the MFMA pipe via
// all-ones A-fragment -- kills the 15-add VALU tree + final shuffle),
// in-register P redistribution (cvt_pk + permlane32_swap). 512 blocks
// XCD-swizzled, 4 waves x 64 q-rows, K/V register-pipelined one tile ahead.
__global__ __launch_bounds__(256, 2) void attn_fwd(const ushort_t* __restrict__ Qf,
                                                   const ushort_t* __restrict__ Kf,
                                                   const ushort_t* __restrict__ Vf,
                                                   ushort_t* __restrict__ Ov) {
    const int tid = threadIdx.x;
    const int lane = tid & 63;
    const int wid = tid >> 6;
    const int lc = lane & 31, lh = lane >> 5;

    const int wg = blockIdx.x;          // 512 blocks
    const int xcd = wg & 7, slot = wg >> 3;
    const int bh = xcd * 8 + (slot >> 3);
    const int qt = slot & 7;            // 8 q-chunks of 256 rows per bh

    const ushort_t* qpb = Qf + (size_t)bh * N_ * HD_;
    const ushort_t* kpb = Kf + (size_t)bh * N_ * HD_;
    const ushort_t* vpb = Vf + (size_t)bh * N_ * HD_;

    const int qblk0 = qt * 8 + wid * 2;

    short8 qf[2][4];
#pragma unroll
    for (int qc = 0; qc < 2; ++qc)
#pragma unroll
        for (int ks = 0; ks < 4; ++ks)
            qf[qc][ks] = *(const short8*)(qpb + ((size_t)(qblk0 + qc) * 4 + ks) * 512 +
                                          lane * 8);

    f32x16 oacc[2][2] = {};
    f32x16 ssum[2] = {};

    uint4v ow;
    ow[0] = 0x3F803F80u; ow[1] = 0x3F803F80u; ow[2] = 0x3F803F80u; ow[3] = 0x3F803F80u;
    const short8 onesf = __builtin_bit_cast(short8, ow);

    short8 kfA[4], kfB[4], vfA[4], vfB[4];
#pragma unroll
    for (int ks = 0; ks < 4; ++ks)
        kfA[ks] = *(const short8*)(kpb + (size_t)ks * 512 + lane * 8);
#pragma unroll
    for (int dt = 0; dt < 2; ++dt)
#pragma unroll
        for (int kb = 0; kb < 2; ++kb)
            vfA[dt * 2 + kb] = *(const short8*)(vpb + ((size_t)dt * 2 + kb) * 512 + lane * 8);

    auto iter = [&](short8(&kfu)[4], short8(&kfp)[4], short8(&vfu)[4], short8(&vfp)[4],
                    int t) {
        f32x16 sacc[2] = {};
        __builtin_amdgcn_s_setprio(1);
#pragma unroll
        for (int ks = 0; ks < 4; ++ks)
#pragma unroll
            for (int qc = 0; qc < 2; ++qc)
                sacc[qc] = __builtin_amdgcn_mfma_f32_32x32x16_bf16(kfu[ks], qf[qc][ks],
                                                                   sacc[qc], 0, 0, 0);
        __builtin_amdgcn_s_setprio(0);

        const int kvn = (t + 1) & 63;
#pragma unroll
        for (int ks = 0; ks < 4; ++ks)
            kfp[ks] = *(const short8*)(kpb + ((size_t)kvn * 4 + ks) * 512 + lane * 8);
#pragma unroll
        for (int dt = 0; dt < 2; ++dt)
#pragma unroll
            for (int kb = 0; kb < 2; ++kb)
                vfp[dt * 2 + kb] = *(const short8*)(vpb + (((size_t)kvn * 2 + dt) * 2 + kb) *
                                                    512 + lane * 8);

#pragma unroll
        for (int qc = 0; qc < 2; ++qc) {
            float p[16];
#pragma unroll
            for (int r = 0; r < 16; ++r) p[r] = __builtin_amdgcn_exp2f(sacc[qc][r]);

            unsigned pk[4][2];
#pragma unroll
            for (int r1 = 0; r1 < 4; ++r1)
#pragma unroll
                for (int c = 0; c < 2; ++c)
                    asm("v_cvt_pk_bf16_f32 %0, %1, %2"
                        : "=v"(pk[r1][c])
                        : "v"(p[4 * r1 + 2 * c]), "v"(p[4 * r1 + 2 * c + 1]));

            short8 pb[2];
#pragma unroll
            for (int kb = 0; kb < 2; ++kb) {
                unsigned a0 = pk[2 * kb][0], b0 = pk[2 * kb + 1][0];
                unsigned a1 = pk[2 * kb][1], b1 = pk[2 * kb + 1][1];
                asm("v_permlane32_swap_b32 %0, %1" : "+v"(a0), "+v"(b0));
                asm("v_permlane32_swap_b32 %0, %1" : "+v"(a1), "+v"(b1));
                uint4v w;
                w[0] = a0; w[1] = a1; w[2] = b0; w[3] = b1;
                pb[kb] = __builtin_bit_cast(short8, w);
            }

            __builtin_amdgcn_s_setprio(1);
            ssum[qc] = __builtin_amdgcn_mfma_f32_32x32x16_bf16(onesf, pb[0], ssum[qc],
                                                               0, 0, 0);
            ssum[qc] = __builtin_amdgcn_mfma_f32_32x32x16_bf16(onesf, pb[1], ssum[qc],
                                                               0, 0, 0);
#pragma unroll
            for (int dt = 0; dt < 2; ++dt)
#pragma unroll
                for (int kb = 0; kb < 2; ++kb)
                    oacc[qc][dt] = __builtin_amdgcn_mfma_f32_32x32x16_bf16(
                        vfu[dt * 2 + kb], pb[kb], oacc[qc][dt], 0, 0, 0);
            __builtin_amdgcn_s_setprio(0);
        }
    };

    for (int t2 = 0; t2 < 64; t2 += 2) {
        iter(kfA, kfB, vfA, vfB, t2);
        iter(kfB, kfA, vfB, vfA, t2 + 1);
    }

    const int b = bh >> 4, h = bh & 15;
#pragma unroll
    for (int qc = 0; qc < 2; ++qc) {
        const float inv = 1.f / ssum[qc][0];
        const int qg = (qblk0 + qc) * 32 + lc;
        ushort_t* orow = Ov + (size_t)(b * N_ + qg) * C_ + h * HD_;
#pragma unroll
        for (int dt = 0; dt < 2; ++dt)
#pragma unroll
            for (int r1 = 0; r1 < 4; ++r1) {
                ushortx4 pkv;
#pragma unroll
                for (int r0 = 0; r0 < 4; ++r0)
                    pkv[r0] = f2bf(oacc[qc][dt][4 * r1 + r0] * inv);
                *(ushortx4*)(orow + dt * 32 + r1 * 8 + lh * 4) = pkv;
            }
    }
}

extern "C" void kernel_launch(void* const* d_in, const int* in_sizes, int n_in,
                              void* d_out, int out_size, void* d_ws, size_t ws_size,
                              hipStream_t stream) {
    const float* x = (const float*)d_in[0];
    const float* wqkv = (const float*)d_in[1];
    const float* wout = (const float*)d_in[2];
    const float* bout = (const float*)d_in[3];
    float* out = (float*)d_out;

    ushort_t* ws = (ushort_t*)d_ws;
    const size_t XN = (size_t)M_TOT * C_;       // 8388608
    const size_t WQN = (size_t)N3_ * C_;        // 3145728
    const size_t WON = (size_t)C_ * C_;         // 1048576
    ushort_t* xbf = ws;                         // also reused as vhat after gemm1
    ushort_t* wqkvb = xbf + XN;
    ushort_t* woutb = wqkvb + WQN;
    ushort_t* karr = woutb + WON;
    ushort_t* varr = karr + XN;
    ushort_t* qarr = varr + XN;
    ushort_t* vhat = xbf;  // alias: x_bf dead after gemm1

    cast3_f32_bf16<<<2048, 256, 0, stream>>>(x, wqkv, wout, xbf, wqkvb, woutb,
                                             (int)(XN / 4), (int)(WQN / 4), (int)(WON / 4));

    gemm4w<0><<<1536, 256, 0, stream>>>(xbf, wqkvb, qarr, karr, varr,
                                        nullptr, nullptr, C_, 24);
    attn_fwd<<<512, 256, 0, stream>>>(qarr, karr, varr, vhat);
    gemm4w<1><<<512, 256, 0, stream>>>(vhat, woutb, nullptr, nullptr, nullptr,
                                       out, bout, C_, 8);
}

// Round 13
// 176.673 us; speedup vs baseline: 1.0667x; 1.0667x over previous
//
#include <hip/hip_runtime.h>

typedef unsigned short ushort_t;
typedef __attribute__((ext_vector_type(8))) short short8;
typedef __attribute__((ext_vector_type(4))) float f32x4;
typedef __attribute__((ext_vector_type(16))) float f32x16;
typedef __attribute__((ext_vector_type(4))) float float4v;
typedef __attribute__((ext_vector_type(4))) unsigned short ushortx4;
typedef __attribute__((ext_vector_type(4))) unsigned int uint4v;

#define AS1 __attribute__((address_space(1)))
#define AS3 __attribute__((address_space(3)))

#define B_ 4
#define N_ 2048
#define C_ 1024
#define H_ 16
#define HD_ 64
#define M_TOT 8192
#define N3_ 3072

// q scale: 1/sqrt(64) * log2(e) so softmax runs in exp2 domain
#define QSCALE 0.18033688011112042f

__device__ __forceinline__ unsigned short f2bf(float f) {
    unsigned int u = __float_as_uint(f);
    u += 0x7fffu + ((u >> 16) & 1u);
    return (unsigned short)(u >> 16);
}

// merged cast: x, w_qkv, w_out -> bf16 in one launch
__global__ __launch_bounds__(256) void cast3_f32_bf16(const float* __restrict__ xa,
                                                      const float* __restrict__ xb,
                                                      const float* __restrict__ xc,
                                                      ushort_t* __restrict__ oa,
                                                      ushort_t* __restrict__ ob,
                                                      ushort_t* __restrict__ oc,
                                                      int n4a, int n4b, int n4c) {
    int i = blockIdx.x * blockDim.x + threadIdx.x;
    const int stride = gridDim.x * blockDim.x;
    const int tot = n4a + n4b + n4c;
    for (; i < tot; i += stride) {
        const float4v* src;
        ushortx4* dst;
        int j = i;
        if (j < n4a) { src = (const float4v*)xa; dst = (ushortx4*)oa; }
        else if ((j -= n4a) < n4b) { src = (const float4v*)xb; dst = (ushortx4*)ob; }
        else { j -= n4b; src = (const float4v*)xc; dst = (ushortx4*)oc; }
        float4v v = src[j];
        ushortx4 o;
        o[0] = f2bf(v[0]); o[1] = f2bf(v[1]); o[2] = f2bf(v[2]); o[3] = f2bf(v[3]);
        dst[j] = o;
    }
}

// Fragment-major layouts for attention (lane = 64-lane wave index, 32x32x16 MFMA):
//  Q/K element (bh, n, hd): blk=n>>5, ks=hd>>4, lane=(n&31)+32*((hd>>3)&1), e=hd&7
//    addr = ((bh*64+blk)*4+ks)*512 + lane*8 + e
//  V element (bh, kv, d): t=kv>>5, dt=d>>5, kb=(kv>>4)&1, lane=(d&31)+32*((kv>>3)&1), e=kv&7
//    addr = (((bh*64+t)*2+dt)*2+kb)*512 + lane*8 + e

// ---------------------------------------------------------------------------
// gemm8p (R11 proven): C = A @ B^T. BM=256, BN=128, BK=64. 512 threads =
// 8 waves (4M x 2N), per-wave 64x64. 2 LDS buffers x 48KB (96KB dynamic).
// Counted s_waitcnt vmcnt(2) once per K-tile (never 0 in steady state),
// 2 raw s_barriers per tile. 2-way-free XOR bank swizzle via pre-swizzled
// global source + linear global_load_lds dest.
// EPI 0: scatter qkv fragment-major (q *QSCALE).  EPI 1: f32 + bias.
// ---------------------------------------------------------------------------
template <int EPI>
__global__ __launch_bounds__(512, 2) void gemm8p(const ushort_t* __restrict__ A,
                                                 const ushort_t* __restrict__ Bw,
                                                 ushort_t* __restrict__ o0,
                                                 ushort_t* __restrict__ o1,
                                                 ushort_t* __restrict__ o2,
                                                 float* __restrict__ outf,
                                                 const float* __restrict__ bias,
                                                 int K, int NBX) {
    extern __shared__ ushort_t smem[];  // 2 * 24576 elems (96 KB)
    const int tid = threadIdx.x;
    const int lane = tid & 63;
    const int wid = tid >> 6;
    const int l15 = lane & 15, lg = lane >> 4;
    const int wr = wid >> 1;        // 0..3 (M)
    const int wc = wid & 1;         // 0..1 (N)

    const int wg = blockIdx.x;
    const int id = (wg & 7) * ((int)gridDim.x >> 3) + (wg >> 3);
    const int by = id / NBX, bx = id - by * NBX;
    const int m0 = by * 256, n0 = bx * 128;

    const int koff = (((lane >> 4) ^ ((lane >> 1) & 3)) << 3);  // read-side swizzle
    const int trow = tid >> 2;                                  // 0..127
    const int slotsrc = (tid & 3) ^ ((tid >> 3) & 3);           // stage-side swizzle

    auto stageA = [&](int q, int tt, int kh, int c) {
        const ushort_t* src = A + (size_t)(m0 + c * 128 + trow) * K + tt * 64 + kh * 32 +
                              slotsrc * 8;
        ushort_t* dst = smem + q * 24576 + kh * 8192 + c * 4096 + tid * 8;
        __builtin_amdgcn_global_load_lds((const AS1 void*)src, (AS3 void*)dst, 16, 0, 0);
    };
    auto stageB = [&](int q, int tt, int kh) {
        const ushort_t* src = Bw + (size_t)(n0 + trow) * K + tt * 64 + kh * 32 + slotsrc * 8;
        ushort_t* dst = smem + q * 24576 + 16384 + kh * 4096 + tid * 8;
        __builtin_amdgcn_global_load_lds((const AS1 void*)src, (AS3 void*)dst, 16, 0, 0);
    };

    f32x4 acc[4][4] = {};

    auto phase = [&](int p, int kh) {
        const ushort_t* Ab = smem + p * 24576 + kh * 8192;
        const ushort_t* Bb = smem + p * 24576 + 16384 + kh * 4096;
        short8 af[4], bfr[4];
#pragma unroll
        for (int rt = 0; rt < 4; ++rt)
            af[rt] = *(const short8*)(Ab + (wr * 64 + rt * 16 + l15) * 32 + koff);
#pragma unroll
        for (int ni = 0; ni < 4; ++ni)
            bfr[ni] = *(const short8*)(Bb + (wc * 64 + ni * 16 + l15) * 32 + koff);
        __builtin_amdgcn_s_setprio(1);
#pragma unroll
        for (int rt = 0; rt < 4; ++rt)
#pragma unroll
            for (int ni = 0; ni < 4; ++ni)
                acc[rt][ni] = __builtin_amdgcn_mfma_f32_16x16x32_bf16(af[rt], bfr[ni],
                                                                      acc[rt][ni], 0, 0, 0);
        __builtin_amdgcn_s_setprio(0);
    };

    stageA(0, 0, 0, 0); stageA(0, 0, 0, 1);
    stageA(0, 0, 1, 0); stageA(0, 0, 1, 1);
    stageB(0, 0, 0);    stageB(0, 0, 1);

    const int NT = K >> 6;
    for (int t = 0; t < NT; ++t) {
        const int p = t & 1, q = p ^ 1;
        if (t + 1 < NT) {
            stageA(q, t + 1, 0, 0); stageA(q, t + 1, 0, 1);
            __builtin_amdgcn_sched_barrier(0);
            asm volatile("s_waitcnt vmcnt(2)");
        } else {
            asm volatile("s_waitcnt vmcnt(0)");
        }
        __builtin_amdgcn_sched_barrier(0);
        __builtin_amdgcn_s_barrier();
        __builtin_amdgcn_sched_barrier(0);
        phase(p, 0);
        if (t + 1 < NT) {
            stageA(q, t + 1, 1, 0); stageA(q, t + 1, 1, 1);
            stageB(q, t + 1, 0);    stageB(q, t + 1, 1);
        }
        __builtin_amdgcn_sched_barrier(0);
        __builtin_amdgcn_s_barrier();
        __builtin_amdgcn_sched_barrier(0);
        phase(p, 1);
    }

    if (EPI == 0) {
        const int sel = bx >> 3;
#pragma unroll
        for (int mi = 0; mi < 4; ++mi) {
            const int r0 = m0 + wr * 64 + mi * 16 + lg * 4;
            const int b = r0 >> 11, n = r0 & 2047;
            const int blk = n >> 5, nlo = n & 31;
#pragma unroll
            for (int ni = 0; ni < 4; ++ni) {
                const int cq = (bx & 7) * 128 + wc * 64 + ni * 16 + l15;
                const int h = cq >> 6, hd = cq & 63;
                const int bh = b * H_ + h;
                f32x4 a = acc[mi][ni];
                if (sel == 2) {
                    size_t base = (((size_t)(bh * 64 + blk) * 2 + (hd >> 5)) * 2 +
                                   ((n >> 4) & 1)) * 512 +
                                  ((hd & 31) + ((n >> 3) & 1) * 32) * 8 + (n & 7);
                    ushortx4 pk;
#pragma unroll
                    for (int j = 0; j < 4; ++j) pk[j] = f2bf(a[j]);
                    *(ushortx4*)(&o2[base]) = pk;
                } else {
                    size_t base = ((size_t)(bh * 64 + blk) * 4 + (hd >> 4)) * 512 +
                                  (nlo + ((hd >> 3) & 1) * 32) * 8 + (hd & 7);
                    if (sel == 0) {
#pragma unroll
                        for (int j = 0; j < 4; ++j) o0[base + j * 8] = f2bf(a[j] * QSCALE);
                    } else {
#pragma unroll
                        for (int j = 0; j < 4; ++j) o1[base + j * 8] = f2bf(a[j]);
                    }
                }
            }
        }
    } else {
#pragma unroll
        for (int ni = 0; ni < 4; ++ni) {
            const int c = n0 + wc * 64 + ni * 16 + l15;
            const float bv = bias[c];
#pragma unroll
            for (int mi = 0; mi < 4; ++mi) {
                const int r0 = m0 + wr * 64 + mi * 16 + lg * 4;
                f32x4 a = acc[mi][ni];
#pragma unroll
                for (int j = 0; j < 4; ++j)
                    outf[(size_t)(r0 + j) * C_ + c] = a[j] + bv;
            }
        }
    }
}

// Flash attention (exact v4 structure, 79.9us proven; VALU srun tree, NO
// ones-MFMA -- R12 showed the extra MFMAs cost +7us). One tweak: QK MFMAs
// grouped qc-major so sacc[0] completes halfway through the cluster, giving
// the scheduler a chance to overlap softmax(qc0) with qc1's matrix-pipe time.
__global__ __launch_bounds__(256, 2) void attn_fwd(const ushort_t* __restrict__ Qf,
                                                   const ushort_t* __restrict__ Kf,
                                                   const ushort_t* __restrict__ Vf,
                                                   ushort_t* __restrict__ Ov) {
    const int tid = threadIdx.x;
    const int lane = tid & 63;
    const int wid = tid >> 6;
    const int lc = lane & 31, lh = lane >> 5;

    const int wg = blockIdx.x;          // 512 blocks
    const int xcd = wg & 7, slot = wg >> 3;
    const int bh = xcd * 8 + (slot >> 3);
    const int qt = slot & 7;

    const ushort_t* qpb = Qf + (size_t)bh * N_ * HD_;
    const ushort_t* kpb = Kf + (size_t)bh * N_ * HD_;
    const ushort_t* vpb = Vf + (size_t)bh * N_ * HD_;

    const int qblk0 = qt * 8 + wid * 2;

    short8 qf[2][4];
#pragma unroll
    for (int qc = 0; qc < 2; ++qc)
#pragma unroll
        for (int ks = 0; ks < 4; ++ks)
            qf[qc][ks] = *(const short8*)(qpb + ((size_t)(qblk0 + qc) * 4 + ks) * 512 +
                                          lane * 8);

    f32x16 oacc[2][2] = {};
    float srun[2] = {0.f, 0.f};

    short8 kfA[4], kfB[4], vfA[4], vfB[4];
#pragma unroll
    for (int ks = 0; ks < 4; ++ks)
        kfA[ks] = *(const short8*)(kpb + (size_t)ks * 512 + lane * 8);
#pragma unroll
    for (int dt = 0; dt < 2; ++dt)
#pragma unroll
        for (int kb = 0; kb < 2; ++kb)
            vfA[dt * 2 + kb] = *(const short8*)(vpb + ((size_t)dt * 2 + kb) * 512 + lane * 8);

    auto iter = [&](short8(&kfu)[4], short8(&kfp)[4], short8(&vfu)[4], short8(&vfp)[4],
                    int t) {
        // QK^T, qc-major: sacc[0] done after first 4 MFMAs
        f32x16 sacc[2] = {};
        __builtin_amdgcn_s_setprio(1);
#pragma unroll
        for (int qc = 0; qc < 2; ++qc)
#pragma unroll
            for (int ks = 0; ks < 4; ++ks)
                sacc[qc] = __builtin_amdgcn_mfma_f32_32x32x16_bf16(kfu[ks], qf[qc][ks],
                                                                   sacc[qc], 0, 0, 0);
        __builtin_amdgcn_s_setprio(0);

        const int kvn = (t + 1) & 63;
#pragma unroll
        for (int ks = 0; ks < 4; ++ks)
            kfp[ks] = *(const short8*)(kpb + ((size_t)kvn * 4 + ks) * 512 + lane * 8);
#pragma unroll
        for (int dt = 0; dt < 2; ++dt)
#pragma unroll
            for (int kb = 0; kb < 2; ++kb)
                vfp[dt * 2 + kb] = *(const short8*)(vpb + (((size_t)kvn * 2 + dt) * 2 + kb) *
                                                    512 + lane * 8);

#pragma unroll
        for (int qc = 0; qc < 2; ++qc) {
            float p[16];
#pragma unroll
            for (int r = 0; r < 16; ++r) p[r] = __builtin_amdgcn_exp2f(sacc[qc][r]);
            float s01 = (p[0] + p[1]) + (p[2] + p[3]);
            float s23 = (p[4] + p[5]) + (p[6] + p[7]);
            float s45 = (p[8] + p[9]) + (p[10] + p[11]);
            float s67 = (p[12] + p[13]) + (p[14] + p[15]);
            srun[qc] += (s01 + s23) + (s45 + s67);

            unsigned pk[4][2];
#pragma unroll
            for (int r1 = 0; r1 < 4; ++r1)
#pragma unroll
                for (int c = 0; c < 2; ++c)
                    asm("v_cvt_pk_bf16_f32 %0, %1, %2"
                        : "=v"(pk[r1][c])
                        : "v"(p[4 * r1 + 2 * c]), "v"(p[4 * r1 + 2 * c + 1]));

            short8 pb[2];
#pragma unroll
            for (int kb = 0; kb < 2; ++kb) {
                unsigned a0 = pk[2 * kb][0], b0 = pk[2 * kb + 1][0];
                unsigned a1 = pk[2 * kb][1], b1 = pk[2 * kb + 1][1];
                asm("v_permlane32_swap_b32 %0, %1" : "+v"(a0), "+v"(b0));
                asm("v_permlane32_swap_b32 %0, %1" : "+v"(a1), "+v"(b1));
                uint4v w;
                w[0] = a0; w[1] = a1; w[2] = b0; w[3] = b1;
                pb[kb] = __builtin_bit_cast(short8, w);
            }

            __builtin_amdgcn_s_setprio(1);
#pragma unroll
            for (int dt = 0; dt < 2; ++dt)
#pragma unroll
                for (int kb = 0; kb < 2; ++kb)
                    oacc[qc][dt] = __builtin_amdgcn_mfma_f32_32x32x16_bf16(
                        vfu[dt * 2 + kb], pb[kb], oacc[qc][dt], 0, 0, 0);
            __builtin_amdgcn_s_setprio(0);
        }
    };

    for (int t2 = 0; t2 < 64; t2 += 2) {
        iter(kfA, kfB, vfA, vfB, t2);
        iter(kfB, kfA, vfB, vfA, t2 + 1);
    }

    const int b = bh >> 4, h = bh & 15;
#pragma unroll
    for (int qc = 0; qc < 2; ++qc) {
        float s = srun[qc];
        s += __shfl_xor(s, 32, 64);
        const float inv = 1.f / s;
        const int qg = (qblk0 + qc) * 32 + lc;
        ushort_t* orow = Ov + (size_t)(b * N_ + qg) * C_ + h * HD_;
#pragma unroll
        for (int dt = 0; dt < 2; ++dt)
#pragma unroll
            for (int r1 = 0; r1 < 4; ++r1) {
                ushortx4 pkv;
#pragma unroll
                for (int r0 = 0; r0 < 4; ++r0)
                    pkv[r0] = f2bf(oacc[qc][dt][4 * r1 + r0] * inv);
                *(ushortx4*)(orow + dt * 32 + r1 * 8 + lh * 4) = pkv;
            }
    }
}

extern "C" void kernel_launch(void* const* d_in, const int* in_sizes, int n_in,
                              void* d_out, int out_size, void* d_ws, size_t ws_size,
                              hipStream_t stream) {
    const float* x = (const float*)d_in[0];
    const float* wqkv = (const float*)d_in[1];
    const float* wout = (const float*)d_in[2];
    const float* bout = (const float*)d_in[3];
    float* out = (float*)d_out;

    ushort_t* ws = (ushort_t*)d_ws;
    const size_t XN = (size_t)M_TOT * C_;       // 8388608
    const size_t WQN = (size_t)N3_ * C_;        // 3145728
    const size_t WON = (size_t)C_ * C_;         // 1048576
    ushort_t* xbf = ws;                         // also reused as vhat after gemm1
    ushort_t* wqkvb = xbf + XN;
    ushort_t* woutb = wqkvb + WQN;
    ushort_t* karr = woutb + WON;
    ushort_t* varr = karr + XN;
    ushort_t* qarr = varr + XN;
    ushort_t* vhat = xbf;  // alias: x_bf dead after gemm1

    cast3_f32_bf16<<<2048, 256, 0, stream>>>(x, wqkv, wout, xbf, wqkvb, woutb,
                                             (int)(XN / 4), (int)(WQN / 4), (int)(WON / 4));

    gemm8p<0><<<768, 512, 98304, stream>>>(xbf, wqkvb, qarr, karr, varr,
                                           nullptr, nullptr, C_, 24);
    attn_fwd<<<512, 256, 0, stream>>>(qarr, karr, varr, vhat);
    gemm8p<1><<<256, 512, 98304, stream>>>(vhat, woutb, nullptr, nullptr, nullptr,
                                           out, bout, C_, 8);
}